// Round 1
// baseline (444.944 us; speedup 1.0000x reference)
//
#include <hip/hip_runtime.h>

#define PN 22536
#define BN 32
#define MN 16
#define CN 81

// ---------------------------------------------------------------------------
// Kernel A: per-image matching. For each (b, p): IoU against the 16 boxes,
// per-prior max/argmax (first-index wins via strict >), and contribution to
// the per-object best-prior argmax (first-index wins via packed key with ~p).
// ---------------------------------------------------------------------------
__global__ __launch_bounds__(256)
void match_kernel(const float* __restrict__ boxes,    // (B,M,4) xyxy
                  const float* __restrict__ priors,   // (P,4) cxcy
                  float* __restrict__ ofp,            // (B,P) overlap_for_each_prior
                  int* __restrict__ obj,              // (B,P) object_for_each_prior
                  unsigned long long* __restrict__ pfo_key) // (B,M) packed argmax
{
    const int b = blockIdx.y;
    const int p = blockIdx.x * 256 + threadIdx.x;

    __shared__ float4 sbox[MN];
    __shared__ float  sarea[MN];
    if (threadIdx.x < MN) {
        float4 bx = reinterpret_cast<const float4*>(boxes)[b * MN + threadIdx.x];
        sbox[threadIdx.x]  = bx;
        sarea[threadIdx.x] = (bx.z - bx.x) * (bx.w - bx.y);
    }
    __syncthreads();

    float x0 = 0.f, y0 = 0.f, x1 = 0.f, y1 = 0.f, ab = 0.f;
    const bool valid = (p < PN);
    if (valid) {
        float4 pc = reinterpret_cast<const float4*>(priors)[p];
        float hw = pc.z / 2.0f, hh = pc.w / 2.0f;   // cxcy_to_xy: c[:2] -/+ c[2:]/2
        x0 = pc.x - hw; y0 = pc.y - hh;
        x1 = pc.x + hw; y1 = pc.y + hh;
        ab = (x1 - x0) * (y1 - y0);                  // area from xy form, as reference
    }

    float iou_m[MN];
    float best = -1.0f;
    int bestm = 0;
    #pragma unroll
    for (int m = 0; m < MN; ++m) {
        float iou = 0.0f;
        if (valid) {
            float4 bx = sbox[m];
            float lx = fmaxf(bx.x, x0), ly = fmaxf(bx.y, y0);
            float rx = fminf(bx.z, x1), ry = fminf(bx.w, y1);
            float inter = fmaxf(rx - lx, 0.0f) * fmaxf(ry - ly, 0.0f);
            iou = inter / (sarea[m] + ab - inter);
        }
        iou_m[m] = iou;
        if (iou > best) { best = iou; bestm = m; }  // strict > => first index wins
    }
    if (valid) {
        ofp[b * PN + p] = best;
        obj[b * PN + p] = bestm;
    }

    // per-object argmax over P: pack (iou_bits, ~p). iou >= 0 so uint order ==
    // float order; ~p makes smaller p win ties (jnp.argmax first-occurrence).
    const int lane = threadIdx.x & 63;
    #pragma unroll
    for (int m = 0; m < MN; ++m) {
        unsigned long long key =
            ((unsigned long long)__float_as_uint(iou_m[m]) << 32) |
            (unsigned long long)(~(unsigned int)p);
        #pragma unroll
        for (int off = 32; off >= 1; off >>= 1) {
            unsigned long long o = __shfl_down(key, (unsigned)off, 64);
            if (o > key) key = o;
        }
        if (lane == 0) atomicMax(&pfo_key[b * MN + m], key);
    }
}

// ---------------------------------------------------------------------------
// Kernel B: the pfo scatter — obj[pfo[m]] = m (sequential m => last-wins for
// duplicate priors, matching scatter semantics), ofp[pfo[m]] = 1.0
// ---------------------------------------------------------------------------
__global__ void scatter_kernel(const unsigned long long* __restrict__ pfo_key,
                               float* __restrict__ ofp, int* __restrict__ obj)
{
    int b = threadIdx.x;
    if (b >= BN) return;
    for (int m = 0; m < MN; ++m) {
        unsigned int low = (unsigned int)pfo_key[b * MN + m];
        int p = (int)(~low);
        obj[b * PN + p] = m;
        ofp[b * PN + p] = 1.0f;
    }
}

// ---------------------------------------------------------------------------
// Kernel C: fused focal + DIoU loss. Thread-per-prior; the 81-class row lives
// in registers (one read, two passes). Block-level partial sums -> partials.
// ---------------------------------------------------------------------------
__global__ __launch_bounds__(256)
void loss_kernel(const float* __restrict__ plocs,   // (B,P,4)
                 const float* __restrict__ scores,  // (B,P,C)
                 const float* __restrict__ boxes,   // (B,M,4)
                 const int*   __restrict__ labels,  // (B,M)
                 const float* __restrict__ priors,  // (P,4) cxcy
                 const float* __restrict__ ofp,
                 const int*   __restrict__ obj,
                 float* __restrict__ partials)      // (gridDim.x, 4)
{
    const int tid = blockIdx.x * 256 + threadIdx.x;
    const int stride = gridDim.x * 256;
    const int R = BN * PN;

    float conf_acc = 0.f, m_cnt = 0.f, loc_acc = 0.f, pos_cnt = 0.f;

    for (int row = tid; row < R; row += stride) {
        float ofp_v = ofp[row];
        bool pos = ofp_v >= 0.5f;            // lab > 0  (labels are all >= 1)
        bool neg = ofp_v < 0.4f;             // lab_neg == -1
        if (!(pos || neg)) continue;

        const float* srow = scores + (size_t)row * CN;
        float r[CN];
        #pragma unroll
        for (int i = 0; i < CN; ++i) r[i] = srow[i];

        float mx = r[0];
        #pragma unroll
        for (int i = 1; i < CN; ++i) mx = fmaxf(mx, r[i]);

        float se = 0.f;
        #pragma unroll
        for (int i = 0; i < CN; ++i) se += expf(r[i] - mx);

        int b = row / PN;
        int obj_v = obj[row];
        int lab = pos ? labels[b * MN + obj_v] : 0;
        float s_lab = srow[lab];             // reload one scalar (L1/L2 hit);
                                             // avoids dynamic index into r[]
        float lp = s_lab - mx - logf(se);    // log_softmax at target class
        float pt = expf(lp);
        float om = 1.0f - pt;
        conf_acc += 0.25f * om * om * (-lp); // FL_ALPHA (1-pt)^2 (-lp_t)
        m_cnt += 1.0f;

        if (pos) {
            int p = row - b * PN;
            float4 g  = reinterpret_cast<const float4*>(plocs)[row];
            float4 pc = reinterpret_cast<const float4*>(priors)[p];
            // gcxgcy_to_cxcy then cxcy_to_xy (divisions as in reference)
            float cx = g.x * pc.z / 10.0f + pc.x;
            float cy = g.y * pc.w / 10.0f + pc.y;
            float w  = expf(g.z / 5.0f) * pc.z;
            float h  = expf(g.w / 5.0f) * pc.w;
            float px0 = cx - w / 2.0f, py0 = cy - h / 2.0f;
            float px1 = cx + w / 2.0f, py1 = cy + h / 2.0f;

            float4 gb = reinterpret_cast<const float4*>(boxes)[b * MN + obj_v];
            float lx = fmaxf(px0, gb.x), ly = fmaxf(py0, gb.y);
            float rx = fminf(px1, gb.z), ry = fminf(py1, gb.w);
            float inter = fmaxf(rx - lx, 0.f) * fmaxf(ry - ly, 0.f);
            float ap = (px1 - px0) * (py1 - py0);
            float ag = (gb.z - gb.x) * (gb.w - gb.y);
            float iou = inter / (ap + ag - inter + 1e-7f);
            float cpx = (px0 + px1) / 2.0f, cpy = (py0 + py1) / 2.0f;
            float cgx = (gb.x + gb.z) / 2.0f, cgy = (gb.y + gb.w) / 2.0f;
            float dx = cpx - cgx, dy = cpy - cgy;
            float d2 = dx * dx + dy * dy;
            float ex0 = fminf(px0, gb.x), ey0 = fminf(py0, gb.y);
            float ex1 = fmaxf(px1, gb.z), ey1 = fmaxf(py1, gb.w);
            float ew = ex1 - ex0, eh = ey1 - ey0;
            float c2 = ew * ew + eh * eh + 1e-7f;
            loc_acc += 1.0f - iou + d2 / c2;
            pos_cnt += 1.0f;
        }
    }

    // wave reduce then cross-wave via LDS; one partial row per block
    #pragma unroll
    for (int off = 32; off >= 1; off >>= 1) {
        conf_acc += __shfl_down(conf_acc, (unsigned)off, 64);
        m_cnt    += __shfl_down(m_cnt,    (unsigned)off, 64);
        loc_acc  += __shfl_down(loc_acc,  (unsigned)off, 64);
        pos_cnt  += __shfl_down(pos_cnt,  (unsigned)off, 64);
    }
    __shared__ float sred[4][4];
    const int lane = threadIdx.x & 63;
    const int w = threadIdx.x >> 6;
    if (lane == 0) {
        sred[w][0] = conf_acc; sred[w][1] = m_cnt;
        sred[w][2] = loc_acc;  sred[w][3] = pos_cnt;
    }
    __syncthreads();
    if (threadIdx.x == 0) {
        float a = 0.f, bsum = 0.f, c = 0.f, d = 0.f;
        #pragma unroll
        for (int i = 0; i < 4; ++i) {
            a += sred[i][0]; bsum += sred[i][1];
            c += sred[i][2]; d += sred[i][3];
        }
        partials[blockIdx.x * 4 + 0] = a;
        partials[blockIdx.x * 4 + 1] = bsum;
        partials[blockIdx.x * 4 + 2] = c;
        partials[blockIdx.x * 4 + 3] = d;
    }
}

// ---------------------------------------------------------------------------
// Kernel D: final deterministic reduction of block partials -> scalar loss
// ---------------------------------------------------------------------------
__global__ __launch_bounds__(256)
void reduce_kernel(const float* __restrict__ partials, int nblk,
                   float* __restrict__ out)
{
    float c = 0.f, mc = 0.f, l = 0.f, pc = 0.f;
    for (int i = threadIdx.x; i < nblk; i += 256) {
        c  += partials[i * 4 + 0];
        mc += partials[i * 4 + 1];
        l  += partials[i * 4 + 2];
        pc += partials[i * 4 + 3];
    }
    #pragma unroll
    for (int off = 32; off >= 1; off >>= 1) {
        c  += __shfl_down(c,  (unsigned)off, 64);
        mc += __shfl_down(mc, (unsigned)off, 64);
        l  += __shfl_down(l,  (unsigned)off, 64);
        pc += __shfl_down(pc, (unsigned)off, 64);
    }
    __shared__ float s[4][4];
    int lane = threadIdx.x & 63, w = threadIdx.x >> 6;
    if (lane == 0) { s[w][0] = c; s[w][1] = mc; s[w][2] = l; s[w][3] = pc; }
    __syncthreads();
    if (threadIdx.x == 0) {
        float C = 0.f, Mc = 0.f, L = 0.f, Pc = 0.f;
        for (int i = 0; i < 4; ++i) {
            C += s[i][0]; Mc += s[i][1]; L += s[i][2]; Pc += s[i][3];
        }
        out[0] = C / fmaxf(Mc, 1.0f) + L / fmaxf(Pc, 1.0f);
    }
}

// ---------------------------------------------------------------------------
extern "C" void kernel_launch(void* const* d_in, const int* in_sizes, int n_in,
                              void* d_out, int out_size, void* d_ws, size_t ws_size,
                              hipStream_t stream)
{
    const float* plocs  = (const float*)d_in[0];  // predicted_locs  (B,P,4)
    const float* scores = (const float*)d_in[1];  // predicted_scores(B,P,C)
    const float* boxes  = (const float*)d_in[2];  // boxes           (B,M,4)
    const int*   labels = (const int*)d_in[3];    // labels          (B,M)
    const float* priors = (const float*)d_in[4];  // priors_cxcy     (P,4)
    float* out = (float*)d_out;

    char* ws = (char*)d_ws;
    unsigned long long* pfo_key = (unsigned long long*)ws;                 // 4 KiB
    float* ofp = (float*)(ws + 4096);                                      // B*P*4
    int*   obj = (int*)(ws + 4096 + (size_t)BN * PN * 4);                  // B*P*4
    float* partials = (float*)(ws + 4096 + 2 * (size_t)BN * PN * 4);       // NBLK*4

    hipMemsetAsync(pfo_key, 0, BN * MN * sizeof(unsigned long long), stream);

    dim3 gA((PN + 255) / 256, BN);
    match_kernel<<<gA, 256, 0, stream>>>(boxes, priors, ofp, obj, pfo_key);
    scatter_kernel<<<1, 64, 0, stream>>>(pfo_key, ofp, obj);

    const int NBLK = 1024;
    loss_kernel<<<NBLK, 256, 0, stream>>>(plocs, scores, boxes, labels, priors,
                                          ofp, obj, partials);
    reduce_kernel<<<1, 256, 0, stream>>>(partials, NBLK, out);
}